// Round 1
// baseline (219.799 us; speedup 1.0000x reference)
//
#include <hip/hip_runtime.h>
#include <stdint.h>

#define N 8192
#define D 256          // elements per row == bytes per fp8 row
#define INV_T 20.0f
#define BM 128
#define BN 128
#define NXB 64         // col-blocks (N/BN)

typedef __attribute__((ext_vector_type(16))) float f32x16;
typedef __attribute__((ext_vector_type(4))) int i32x4;
typedef __attribute__((ext_vector_type(8))) int i32x8;

typedef __attribute__((address_space(3))) uint32_t lds_u32;
typedef __attribute__((address_space(1))) const uint32_t gbl_u32;

// Kernel 1: per-row fp32 normalize -> fp8 e4m3 copies (HW cvt, OCP on gfx950);
// c[i] = (e_i . p_i)/T exact fp32.
__global__ __launch_bounds__(256) void normalize_kernel(
    const float* __restrict__ e, const float* __restrict__ p, const float* __restrict__ n,
    uint32_t* __restrict__ eb, uint32_t* __restrict__ pb, uint32_t* __restrict__ nb,
    float* __restrict__ cbuf) {
  const int tid = threadIdx.x;
  const int wave = tid >> 6, lane = tid & 63;
  const int row = blockIdx.x * 4 + wave;          // one wave per row

  const float4 ev = ((const float4*)(e + (size_t)row * D))[lane];
  const float4 pv = ((const float4*)(p + (size_t)row * D))[lane];
  const float4 nv = ((const float4*)(n + (size_t)row * D))[lane];

  float sse = ev.x*ev.x + ev.y*ev.y + ev.z*ev.z + ev.w*ev.w;
  float ssp = pv.x*pv.x + pv.y*pv.y + pv.z*pv.z + pv.w*pv.w;
  float ssn = nv.x*nv.x + nv.y*nv.y + nv.z*nv.z + nv.w*nv.w;
  float dep = ev.x*pv.x + ev.y*pv.y + ev.z*pv.z + ev.w*pv.w;
#pragma unroll
  for (int m = 1; m < 64; m <<= 1) {
    sse += __shfl_xor(sse, m);
    ssp += __shfl_xor(ssp, m);
    ssn += __shfl_xor(ssn, m);
    dep += __shfl_xor(dep, m);
  }
  const float se = 1.0f / fmaxf(sqrtf(sse), 1e-8f);
  const float sp = 1.0f / fmaxf(sqrtf(ssp), 1e-8f);
  const float sn = 1.0f / fmaxf(sqrtf(ssn), 1e-8f);

  int ue = __builtin_amdgcn_cvt_pk_fp8_f32(ev.x*se, ev.y*se, 0, false);
  ue     = __builtin_amdgcn_cvt_pk_fp8_f32(ev.z*se, ev.w*se, ue, true);
  int up = __builtin_amdgcn_cvt_pk_fp8_f32(pv.x*sp, pv.y*sp, 0, false);
  up     = __builtin_amdgcn_cvt_pk_fp8_f32(pv.z*sp, pv.w*sp, up, true);
  int un = __builtin_amdgcn_cvt_pk_fp8_f32(nv.x*sn, nv.y*sn, 0, false);
  un     = __builtin_amdgcn_cvt_pk_fp8_f32(nv.z*sn, nv.w*sn, un, true);
  eb[row * 64 + lane] = (uint32_t)ue;             // 64 uints = 256 fp8 bytes per row
  pb[row * 64 + lane] = (uint32_t)up;
  nb[row * 64 + lane] = (uint32_t)un;

  if (lane == 0) cbuf[row] = dep * se * sp * INV_T;
}

// Kernel 2: 128x128-tile fp8 GEMM (X @ Y^T) with fused exp row-sums.
//  - FULL K=256 staged once into LDS (no K loop, ONE barrier in the hot path).
//    66.8 KB LDS -> 2 blocks/CU ping-pong: one block stages while the other computes.
//  - MX-scaled MFMA 32x32x64_f8f6f4 (fmt 0 = OCP e4m3) with unit scales 0x7F (=2^0):
//    exact same math as the non-scaled fp8 op but 2x the rate (~4.7 PF vs ~2.2 PF).
//  - LDS swizzle: 16B-group gg of row r stored at slot gg ^ (r & 15). Each b128
//    wave-read then hits every bank exactly 8x over its 8-clk minimum (conflict-free).
//    The K-order permutation is identical for A and B fragments -> dot unchanged
//    (any consistent K permutation is absorbed by the commutative sum; scales are all 1).
//  - Wave tiles 64x64 (2x2 frag reps): per-block LDS reads 128 KB (was 160 KB).
__global__ __launch_bounds__(256, 2) void simexp_kernel(
    const uint8_t* __restrict__ eb, const uint8_t* __restrict__ pb,
    const uint8_t* __restrict__ nb, const float* __restrict__ cbuf,
    float* __restrict__ part) {
  __shared__ uint8_t As[BM * D];    // 32 KB, full-K A tile (swizzled)
  __shared__ uint8_t Bs[BN * D];    // 32 KB, full-K B tile (swizzled)
  __shared__ float cs[BM];          // 512 B
  __shared__ float sm[BM][2];       // 1 KB: per-row partial from each column-half wave

  const int z = blockIdx.z;
  const uint8_t* __restrict__ A = z ? pb : eb;
  const uint8_t* __restrict__ B = z ? eb : nb;

  const int tid = threadIdx.x;
  const int wave = tid >> 6, lane = tid & 63;
  const int lane31 = lane & 31, half = lane >> 5;
  const int rowTile = blockIdx.x * BM, colblk = blockIdx.y;
  const int colTile = colblk * BN;

  // ---- one-shot staging: 2048 16B chunks per matrix, 8 per thread ----
  // LDS dest is linear (wave-uniform base + lane*16); the swizzle is applied by
  // pre-permuting the per-lane GLOBAL source address (both-sides-or-neither rule).
#pragma unroll
  for (int i = 0; i < 8; ++i) {
    const int c = i * 256 + tid;
    const int r = c >> 4, sl = c & 15;
    const int gg = sl ^ (r & 15);               // swizzled SOURCE group
    __builtin_amdgcn_global_load_lds(
        (gbl_u32*)(A + (size_t)(rowTile + r) * D + gg * 16),
        (lds_u32*)&As[c * 16], 16, 0, 0);
  }
#pragma unroll
  for (int i = 0; i < 8; ++i) {
    const int c = i * 256 + tid;
    const int r = c >> 4, sl = c & 15;
    const int gg = sl ^ (r & 15);
    __builtin_amdgcn_global_load_lds(
        (gbl_u32*)(B + (size_t)(colTile + r) * D + gg * 16),
        (lds_u32*)&Bs[c * 16], 16, 0, 0);
  }
  if (tid < BM) cs[tid] = cbuf[rowTile + tid];

  const int wr = wave >> 1, wc = wave & 1;      // wave -> 64x64 sub-tile (wr, wc)
  const int ra0 = wr * 64 + lane31;             // A rows for mi=0 / mi=1: ra0, ra0+32
  const int cb0 = wc * 64 + lane31;             // B cols for ni=0 / ni=1: cb0, cb0+32

  f32x16 acc[2][2];
#pragma unroll
  for (int mi = 0; mi < 2; ++mi)
#pragma unroll
    for (int ni = 0; ni < 2; ++ni)
#pragma unroll
      for (int r = 0; r < 16; ++r) acc[mi][ni][r] = 0.0f;

  __syncthreads();   // drain staging (compiler emits vmcnt(0)+lgkmcnt(0) here)

  // ---- K loop: 4 steps of K=64, zero barriers ----
#pragma unroll
  for (int s = 0; s < 4; ++s) {
    const int g0 = s * 4 + half * 2;            // this lane's two logical 16B-groups
    i32x8 a[2], b[2];
#pragma unroll
    for (int mi = 0; mi < 2; ++mi) {
      const int r = ra0 + mi * 32, m = r & 15;
      const i32x4 lo = *(const i32x4*)&As[r * D + ((g0 ^ m) * 16)];
      const i32x4 hi = *(const i32x4*)&As[r * D + (((g0 + 1) ^ m) * 16)];
      a[mi] = (i32x8){lo[0], lo[1], lo[2], lo[3], hi[0], hi[1], hi[2], hi[3]};
    }
#pragma unroll
    for (int ni = 0; ni < 2; ++ni) {
      const int r = cb0 + ni * 32, m = r & 15;
      const i32x4 lo = *(const i32x4*)&Bs[r * D + ((g0 ^ m) * 16)];
      const i32x4 hi = *(const i32x4*)&Bs[r * D + (((g0 + 1) ^ m) * 16)];
      b[ni] = (i32x8){lo[0], lo[1], lo[2], lo[3], hi[0], hi[1], hi[2], hi[3]};
    }
#pragma unroll
    for (int mi = 0; mi < 2; ++mi)
#pragma unroll
      for (int ni = 0; ni < 2; ++ni)
        acc[mi][ni] = __builtin_amdgcn_mfma_scale_f32_32x32x64_f8f6f4(
            a[mi], b[ni], acc[mi][ni],
            0 /*cbsz: A=fp8 e4m3*/, 0 /*blgp: B=fp8 e4m3*/,
            0, 0x7F7F7F7F /*scaleA = 1.0*/, 0, 0x7F7F7F7F /*scaleB = 1.0*/);
  }

  // ---- epilogue: exp + row-sum over this wave's 64 cols ----
  // 32x32 C/D layout: col=lane&31, row=(reg&3)+8*(reg>>2)+4*(lane>>5) (m74/m101).
#pragma unroll
  for (int mi = 0; mi < 2; ++mi) {
#pragma unroll
    for (int reg = 0; reg < 16; ++reg) {
      const int rlocal = wr * 64 + mi * 32 + (reg & 3) + 8 * (reg >> 2) + 4 * half;
      const float cv = cs[rlocal];
      float v = __expf(acc[mi][0][reg] * INV_T - cv) +
                __expf(acc[mi][1][reg] * INV_T - cv);
      v += __shfl_xor(v, 1);
      v += __shfl_xor(v, 2);
      v += __shfl_xor(v, 4);
      v += __shfl_xor(v, 8);
      v += __shfl_xor(v, 16);
      if (lane31 == 0) sm[rlocal][wc] = v;      // rows disjoint across (wr,mi,reg,half)
    }
  }
  __syncthreads();
  if (tid < BM)
    part[((size_t)(z * NXB + colblk)) * N + rowTile + tid] = sm[tid][0] + sm[tid][1];
}

// Kernel 3: per-row sum of 64 partials -> log/log1p -> 64 block partials.
__global__ __launch_bounds__(256) void reduce1_kernel(const float* __restrict__ part,
                                                      float* __restrict__ partials) {
  const int bid = blockIdx.x;              // 64 blocks
  const int z = bid >> 5;
  const int row = (bid & 31) * 256 + threadIdx.x;
  float s = 0.0f;
#pragma unroll 8
  for (int x = 0; x < NXB; ++x)
    s += part[((size_t)(z * NXB + x)) * N + row];
  float val = z ? logf(s) : log1pf(s);
#pragma unroll
  for (int m = 1; m < 64; m <<= 1) val += __shfl_xor(val, m);
  __shared__ float sm[4];
  if ((threadIdx.x & 63) == 0) sm[threadIdx.x >> 6] = val;
  __syncthreads();
  if (threadIdx.x == 0) partials[bid] = sm[0] + sm[1] + sm[2] + sm[3];
}

// Kernel 4: final 64-way sum -> mean loss.
__global__ __launch_bounds__(64) void reduce2_kernel(const float* __restrict__ partials,
                                                     float* __restrict__ out) {
  float v = partials[threadIdx.x];
#pragma unroll
  for (int m = 1; m < 64; m <<= 1) v += __shfl_xor(v, m);
  if (threadIdx.x == 0) out[0] = v * (1.0f / (float)N);
}

extern "C" void kernel_launch(void* const* d_in, const int* in_sizes, int n_in,
                              void* d_out, int out_size, void* d_ws, size_t ws_size,
                              hipStream_t stream) {
  const float* e = (const float*)d_in[0];
  const float* p = (const float*)d_in[1];
  const float* n = (const float*)d_in[2];

  char* w = (char*)d_ws;
  uint8_t* eb = (uint8_t*)w;                                     // 2 MB
  uint8_t* pb = eb + (size_t)N * D;                              // 2 MB
  uint8_t* nb = pb + (size_t)N * D;                              // 2 MB
  float* cbuf = (float*)(nb + (size_t)N * D);                    // 32 KB
  float* part = cbuf + N;                                        // 4 MB
  float* partials = part + (size_t)2 * NXB * N;                  // 256 B

  normalize_kernel<<<N / 4, 256, 0, stream>>>(e, p, n, (uint32_t*)eb, (uint32_t*)pb,
                                              (uint32_t*)nb, cbuf);
  simexp_kernel<<<dim3(N / BM, N / BN, 2), 256, 0, stream>>>(eb, pb, nb, cbuf, part);
  reduce1_kernel<<<64, 256, 0, stream>>>(part, partials);
  reduce2_kernel<<<1, 64, 0, stream>>>(partials, (float*)d_out);
}